// Round 5
// baseline (457.447 us; speedup 1.0000x reference)
//
#include <hip/hip_runtime.h>
#include <hip/hip_bf16.h>
#include <stdint.h>

// Int8Linear: per-row symmetric int8 quant (w per-output-channel, x per-token),
// int8 GEMM (exact int32 accum via MFMA i8), fused dequant + bf16 bias epilogue.
// M=8192, K=4096, N=4096 for this problem instance.
//
// R8 == R7 resubmitted verbatim (R7 bench died to a container-acquisition
// failure before executing; audit found no hang/crash hazard in the kernel).
//
// R7 changes vs R6:
//  - R6's 4-phase lockstep REVERTED (regressed 171->188: only 8 waves/CU
//    resident -> barriers fully exposed; phase-split needs wave slack).
//  - Occupancy unlock: per-wave tile 128x64 -> 64x64 (acc 128 -> 64 AGPRs,
//    register cap was 2 waves/SIMD), block tile 256x256 -> 256x128,
//    BKB 128 -> 64 (LDS 128 KB -> 48 KB). Now 2 blocks/CU x 8 waves
//    = 4 waves/SIMD; cross-block overlap hides the tile-end drain (m114).
//  - Schedule = R5's verified minimal form: ONE vmcnt(0)+s_barrier per
//    K-tile, prefetch stages issued mid-tile into buf^1.

using i32x4  = __attribute__((ext_vector_type(4))) int;
using i32x16 = __attribute__((ext_vector_type(16))) int;

#define BM 256
#define BN 128
#define BKB 64    // K-bytes (= int8 k-elems) per LDS tile

// ---------------------------------------------------------------------------
// Fused per-row quantization for both W [N,K] and X [M,K]; one WAVE per row.
// ---------------------------------------------------------------------------
__global__ __launch_bounds__(256) void quant_rows_wave(
    const float* __restrict__ w_in, const float* __restrict__ x_in,
    int8_t* __restrict__ w_q, int8_t* __restrict__ x_q,
    float* __restrict__ w_s, float* __restrict__ x_s,
    int nw, int nrows, int K)
{
    const int wave_id = (int)((blockIdx.x * (unsigned)blockDim.x + threadIdx.x) >> 6);
    if (wave_id >= nrows) return;
    const int lane = threadIdx.x & 63;

    const bool is_w = (wave_id < nw);
    const int row = is_w ? wave_id : (wave_id - nw);
    const float* r = (is_w ? w_in : x_in) + (size_t)row * K;
    int8_t* qout   = (is_w ? w_q : x_q) + (size_t)row * K;
    float* scales  = is_w ? w_s : x_s;

    float4 v[16];
#pragma unroll
    for (int i = 0; i < 16; ++i)
        v[i] = *(const float4*)(r + i * 256 + lane * 4);

    float amax = 0.f;
#pragma unroll
    for (int i = 0; i < 16; ++i) {
        amax = fmaxf(amax, fmaxf(fmaxf(fabsf(v[i].x), fabsf(v[i].y)),
                                 fmaxf(fabsf(v[i].z), fabsf(v[i].w))));
    }

#pragma unroll
    for (int off = 32; off >= 1; off >>= 1)
        amax = fmaxf(amax, __shfl_xor(amax, off));

    const float scale = fmaxf(amax / 127.0f, 1e-12f);
    if (lane == 0) scales[row] = scale;
    const float inv = 1.0f / scale;

#pragma unroll
    for (int i = 0; i < 16; ++i) {
        float q0 = fminf(fmaxf(rintf(v[i].x * inv), -128.f), 127.f);
        float q1 = fminf(fmaxf(rintf(v[i].y * inv), -128.f), 127.f);
        float q2 = fminf(fmaxf(rintf(v[i].z * inv), -128.f), 127.f);
        float q3 = fminf(fmaxf(rintf(v[i].w * inv), -128.f), 127.f);
        union { signed char c[4]; int i32; } u;
        u.c[0] = (signed char)(int)q0;
        u.c[1] = (signed char)(int)q1;
        u.c[2] = (signed char)(int)q2;
        u.c[3] = (signed char)(int)q3;
        *(int*)(qout + i * 256 + lane * 4) = u.i32;
    }
}

// ---------------------------------------------------------------------------
// int8 GEMM: C[M][N] = A[M][K] . B[N][K]^T, int32 accum, fused dequant.
// 256x128 tile, BK=64 i8 (64B rows), 8 waves (4M x 2N, 64x64 each),
// 32x32x32 i8 MFMA, double-buffered LDS (48 KB), 2 blocks/CU.
//
// LDS layout: row-major [rows][64 B], 16B chunks swizzled:
//   phys_chunk = log_chunk ^ (row & 3)
// Staged via global_load_lds (linear dest: thread t -> byte t*16, i.e.
// row = t/4 (+128 per round for A), phys_chunk = t&3) with the INVERSE
// permutation on the per-thread global source chunk:
//   log_chunk = (t&3) ^ ((t>>2)&3)   (row offsets are 0 mod 4, drop out).
//
// Frag reads (32x32x32 i8): lane reads 16B at row = base + (lane&31),
//   log_chunk = ks*2 + (lane>>5), phys = log_chunk ^ (row&3).
//   Bank check: 64 lanes cover all 8 (row&1, phys) 16B slots evenly ->
//   8 accesses/bank = the 1KB minimum, conflict-free.
// C/D: col = lane&31, row = (reg&3) + 8*(reg>>2) + 4*(lane>>5)  [m74/m101]
//
// Sync: ONE [s_waitcnt vmcnt(0); s_barrier] per K-tile (R5-verified).
// Stages write buf^1 only (never read this tile); all reads of buf^1
// completed before the previous tile's closing barrier (MFMA data deps).
// ---------------------------------------------------------------------------
__global__ __launch_bounds__(512, 4) void gemm_i8_256x128(
    const int8_t* __restrict__ A,   // [M][K] x_i8
    const int8_t* __restrict__ B,   // [N][K] w_i8
    const float*  __restrict__ xs,  // [M]
    const float*  __restrict__ ws,  // [N]
    const float*  __restrict__ bias,// [N]
    float*        __restrict__ out, // [M][N] fp32
    int M, int N, int K)
{
    __shared__ int8_t sA[2][BM * BKB];   // 2 x 16 KiB
    __shared__ int8_t sB[2][BN * BKB];   // 2 x  8 KiB

    const int tid   = threadIdx.x;
    const int wave  = tid >> 6;
    const int lane  = tid & 63;
    const int l31   = lane & 31;
    const int lhalf = lane >> 5;        // 0/1
    const int rot   = l31 & 3;          // read-side swizzle rotation

    const int bm = blockIdx.y * BM;
    const int bn = blockIdx.x * BN;
    const int wm = (wave >> 1) * 64;    // 4 M-waves
    const int wn = (wave & 1) * 64;     // 2 N-waves

    i32x16 acc[2][2];                   // [msub][n] -- 64 AGPRs total
#pragma unroll
    for (int q = 0; q < 2; ++q)
#pragma unroll
        for (int n = 0; n < 2; ++n)
#pragma unroll
            for (int r = 0; r < 16; ++r) acc[q][n][r] = 0;

    // staging source (inverse-swizzled chunk per thread)
    const int srow = tid >> 2;                               // 0..127
    const int soff = (((tid & 3) ^ ((tid >> 2) & 3)) << 4);
    const int8_t* aS = A + (size_t)(bm + srow) * K + soff;
    const int8_t* bS = B + (size_t)(bn + srow) * K + soff;
    const size_t rstepA = (size_t)128 * K;   // 128 rows per A load round

    const int NT = K / BKB;

#define STAGE_A(SRC, DST)                                                    \
    {                                                                        \
        _Pragma("unroll")                                                    \
        for (int l = 0; l < 2; ++l)                                          \
            __builtin_amdgcn_global_load_lds(                                \
                (const __attribute__((address_space(1))) void*)((SRC) + l * rstepA), \
                (__attribute__((address_space(3))) void*)((DST) + l * 8192 + tid * 16), \
                16, 0, 0);                                                   \
    }
#define STAGE_B(SRC, DST)                                                    \
    __builtin_amdgcn_global_load_lds(                                        \
        (const __attribute__((address_space(1))) void*)(SRC),                \
        (__attribute__((address_space(3))) void*)((DST) + tid * 16), 16, 0, 0);

    // prologue: stage tile 0 into buffer 0
    STAGE_A(aS, &sA[0][0]);
    STAGE_B(bS, &sB[0][0]);
    asm volatile("s_waitcnt vmcnt(0)" ::: "memory");
    __builtin_amdgcn_s_barrier();
    asm volatile("" ::: "memory");

    for (int t = 0; t < NT; ++t) {
        const int cur = t & 1;
        const int8_t* cA = &sA[cur][0];
        const int8_t* cB = &sB[cur][0];
        int8_t* nA = &sA[cur ^ 1][0];
        int8_t* nB = &sB[cur ^ 1][0];
        const size_t knext = (size_t)(t + 1) * BKB;
        const bool pf = (t + 1 < NT);   // uniform

        // B-frags for the whole tile (4 x ds_read_b128)
        i32x4 bf[2][2];
#pragma unroll
        for (int n = 0; n < 2; ++n)
#pragma unroll
            for (int ks = 0; ks < 2; ++ks) {
                const int row = wn + n * 32 + l31;
                bf[n][ks] = *(const i32x4*)(cB + row * BKB +
                                            ((((ks << 1) | lhalf) ^ rot) << 4));
            }

#pragma unroll
        for (int q = 0; q < 2; ++q) {
            // A-frags for M-subtile q (2 x ds_read_b128)
            i32x4 af[2];
            {
                const int arow = wm + q * 32 + l31;
#pragma unroll
                for (int ks = 0; ks < 2; ++ks)
                    af[ks] = *(const i32x4*)(cA + arow * BKB +
                                             ((((ks << 1) | lhalf) ^ rot) << 4));
            }

            // prefetch next tile: A at q=0, B at q=1; flies under MFMA
            if (q == 0 && pf) STAGE_A(aS + knext, nA);
            if (q == 1 && pf) STAGE_B(bS + knext, nB);

            // 4 MFMA: M-subtile q x 2 N-tiles x 2 k-slices
#pragma unroll
            for (int n = 0; n < 2; ++n)
#pragma unroll
                for (int ks = 0; ks < 2; ++ks)
                    acc[q][n] = __builtin_amdgcn_mfma_i32_32x32x32_i8(
                        af[ks], bf[n][ks], acc[q][n], 0, 0, 0);
        }

        // tile boundary: drain this tile's prefetch, swap buffers
        asm volatile("s_waitcnt vmcnt(0)" ::: "memory");
        __builtin_amdgcn_s_barrier();
        asm volatile("" ::: "memory");
    }
#undef STAGE_A
#undef STAGE_B

    // Epilogue: out = fp32( bf16( bf16(acc*xs*ws) + bf16(bias) ) )
#pragma unroll
    for (int n = 0; n < 2; ++n) {
        const int col = bn + wn + n * 32 + l31;
        const float wsv = ws[col];
        const float bsv = __bfloat162float(__float2bfloat16(bias[col]));
#pragma unroll
        for (int q = 0; q < 2; ++q) {
            const int rowbase = bm + wm + q * 32 + 4 * lhalf;
#pragma unroll
            for (int r = 0; r < 16; ++r) {
                const int row = rowbase + (r & 3) + 8 * (r >> 2);
                const float v = (float)acc[q][n][r] * xs[row] * wsv;
                const float vb = __bfloat162float(__float2bfloat16(v));
                const float res = __bfloat162float(__float2bfloat16(vb + bsv));
                out[(size_t)row * N + col] = res;
            }
        }
    }
}

// ---------------------------------------------------------------------------
extern "C" void kernel_launch(void* const* d_in, const int* in_sizes, int n_in,
                              void* d_out, int out_size, void* d_ws, size_t ws_size,
                              hipStream_t stream)
{
    const float* x    = (const float*)d_in[0];   // [B,S,K] fp32
    const float* wfp  = (const float*)d_in[1];   // [N,K] fp32
    const float* bias = (const float*)d_in[2];   // [N] fp32
    float* out = (float*)d_out;                  // [M,N] fp32

    const int N = in_sizes[2];
    const int K = in_sizes[1] / N;
    const int M = in_sizes[0] / K;

    // workspace layout: w_i8[N*K] | x_i8[M*K] | w_scales[N] | x_scales[M]
    int8_t* w_i8 = (int8_t*)d_ws;
    int8_t* x_i8 = w_i8 + (size_t)N * K;
    float* w_scales = (float*)(x_i8 + (size_t)M * K);
    float* x_scales = w_scales + N;

    const int nrows = N + M;                     // one wave per row
    const int nblocks = (nrows + 3) / 4;         // 4 waves / 256-thread block
    quant_rows_wave<<<nblocks, 256, 0, stream>>>(wfp, x, w_i8, x_i8,
                                                 w_scales, x_scales,
                                                 N, nrows, K);

    dim3 grid(N / BN, M / BM);
    gemm_i8_256x128<<<grid, 512, 0, stream>>>(x_i8, w_i8, x_scales, w_scales,
                                              bias, out, M, N, K);
}

// Round 6
// 453.087 us; speedup vs baseline: 1.0096x; 1.0096x over previous
//
#include <hip/hip_runtime.h>
#include <hip/hip_bf16.h>
#include <stdint.h>

// Int8Linear: per-row symmetric int8 quant (w per-output-channel, x per-token),
// int8 GEMM (exact int32 accum via MFMA i8), fused dequant + bf16 bias epilogue.
// M=8192, K=4096, N=4096 for this problem instance.
//
// R9 changes vs R8 (swizzle fix ONLY; geometry/schedule identical):
//  - R8's XOR chunk swizzle (phys = log ^ (row&3)) halved effective LDS banks:
//    with 64B rows, bank-group = (row&1, phys), and XOR preserves bit0, so
//    phys determined row&1 -> each half-wave touched only 4/8 bank groups.
//    Measured: SQ_LDS_BANK_CONFLICT 1.26e7 (R5) -> 5.03e7 (R8) = 38% of
//    runtime in conflict stalls; MfmaUtil fell 36 -> 28 despite 40% occupancy.
//  - Fix: ADD-rotation sw(row) = (row + (row>>2)) & 3, phys = (log + sw) & 3.
//    For row=0..7 the pair (row&1, phys) covers all 8 bank groups exactly
//    once -> all 32 banks busy in every half-wave. Stage-side inverse:
//    src log = ((t&3) - (t>>2) - (t>>4)) & 3 (l-independent for all rounds).

using i32x4  = __attribute__((ext_vector_type(4))) int;
using i32x16 = __attribute__((ext_vector_type(16))) int;

#define BM 256
#define BN 128
#define BKB 64    // K-bytes (= int8 k-elems) per LDS tile

// ---------------------------------------------------------------------------
// Fused per-row quantization for both W [N,K] and X [M,K]; one WAVE per row.
// ---------------------------------------------------------------------------
__global__ __launch_bounds__(256) void quant_rows_wave(
    const float* __restrict__ w_in, const float* __restrict__ x_in,
    int8_t* __restrict__ w_q, int8_t* __restrict__ x_q,
    float* __restrict__ w_s, float* __restrict__ x_s,
    int nw, int nrows, int K)
{
    const int wave_id = (int)((blockIdx.x * (unsigned)blockDim.x + threadIdx.x) >> 6);
    if (wave_id >= nrows) return;
    const int lane = threadIdx.x & 63;

    const bool is_w = (wave_id < nw);
    const int row = is_w ? wave_id : (wave_id - nw);
    const float* r = (is_w ? w_in : x_in) + (size_t)row * K;
    int8_t* qout   = (is_w ? w_q : x_q) + (size_t)row * K;
    float* scales  = is_w ? w_s : x_s;

    float4 v[16];
#pragma unroll
    for (int i = 0; i < 16; ++i)
        v[i] = *(const float4*)(r + i * 256 + lane * 4);

    float amax = 0.f;
#pragma unroll
    for (int i = 0; i < 16; ++i) {
        amax = fmaxf(amax, fmaxf(fmaxf(fabsf(v[i].x), fabsf(v[i].y)),
                                 fmaxf(fabsf(v[i].z), fabsf(v[i].w))));
    }

#pragma unroll
    for (int off = 32; off >= 1; off >>= 1)
        amax = fmaxf(amax, __shfl_xor(amax, off));

    const float scale = fmaxf(amax / 127.0f, 1e-12f);
    if (lane == 0) scales[row] = scale;
    const float inv = 1.0f / scale;

#pragma unroll
    for (int i = 0; i < 16; ++i) {
        float q0 = fminf(fmaxf(rintf(v[i].x * inv), -128.f), 127.f);
        float q1 = fminf(fmaxf(rintf(v[i].y * inv), -128.f), 127.f);
        float q2 = fminf(fmaxf(rintf(v[i].z * inv), -128.f), 127.f);
        float q3 = fminf(fmaxf(rintf(v[i].w * inv), -128.f), 127.f);
        union { signed char c[4]; int i32; } u;
        u.c[0] = (signed char)(int)q0;
        u.c[1] = (signed char)(int)q1;
        u.c[2] = (signed char)(int)q2;
        u.c[3] = (signed char)(int)q3;
        *(int*)(qout + i * 256 + lane * 4) = u.i32;
    }
}

// ---------------------------------------------------------------------------
// int8 GEMM: C[M][N] = A[M][K] . B[N][K]^T, int32 accum, fused dequant.
// 256x128 tile, BK=64 i8 (64B rows), 8 waves (4M x 2N, 64x64 each),
// 32x32x32 i8 MFMA, double-buffered LDS (48 KB), 2 blocks/CU.
//
// LDS layout: row-major [rows][64 B], 16B chunks with ADD-rotation swizzle:
//   sw(row) = (row + (row>>2)) & 3;  phys_chunk = (log_chunk + sw) & 3
// Bank check (64B rows => bank-group = (row&1, phys), 8 groups x 4 banks):
//   for fixed log, rows 0..7 give (row&1, phys) = (0,0)(1,1)(0,2)(1,3)
//   (0,1)(1,2)(0,3)(1,0) -- all 8 groups exactly once => conflict-free in
//   every half-wave. (R8's XOR swizzle hit only 4 groups/half-wave.)
// Staged via global_load_lds (linear dest: thread t -> byte t*16, i.e.
// row = t>>2 (+128/round for A), phys = t&3) with the INVERSE rotation on
// the per-thread global source chunk:
//   log = (phys - sw(row)) & 3 = ((t&3) - (t>>2) - (t>>4)) & 3
//   (row offsets 128*l contribute 0 mod 4 to both terms -> l-independent).
//
// Frag reads (32x32x32 i8): lane reads 16B at row = base + (lane&31),
//   log = ks*2 + (lane>>5); base is a multiple of 32 so
//   sw = ((lane&31) + ((lane&31)>>2)) & 3, lane-constant.
// C/D: col = lane&31, row = (reg&3) + 8*(reg>>2) + 4*(lane>>5)  [m74/m101]
//
// Sync: ONE [s_waitcnt vmcnt(0); s_barrier] per K-tile (R5-verified).
// Stages write buf^1 only (never read this tile); all reads of buf^1
// completed before the previous tile's closing barrier (MFMA data deps).
// ---------------------------------------------------------------------------
__global__ __launch_bounds__(512, 4) void gemm_i8_256x128(
    const int8_t* __restrict__ A,   // [M][K] x_i8
    const int8_t* __restrict__ B,   // [N][K] w_i8
    const float*  __restrict__ xs,  // [M]
    const float*  __restrict__ ws,  // [N]
    const float*  __restrict__ bias,// [N]
    float*        __restrict__ out, // [M][N] fp32
    int M, int N, int K)
{
    __shared__ int8_t sA[2][BM * BKB];   // 2 x 16 KiB
    __shared__ int8_t sB[2][BN * BKB];   // 2 x  8 KiB

    const int tid   = threadIdx.x;
    const int wave  = tid >> 6;
    const int lane  = tid & 63;
    const int l31   = lane & 31;
    const int lhalf = lane >> 5;        // 0/1
    const int rot4  = (l31 + (l31 >> 2)) & 3;   // read-side rotation sw(row)

    const int bm = blockIdx.y * BM;
    const int bn = blockIdx.x * BN;
    const int wm = (wave >> 1) * 64;    // 4 M-waves
    const int wn = (wave & 1) * 64;     // 2 N-waves

    i32x16 acc[2][2];                   // [msub][n] -- 64 AGPRs total
#pragma unroll
    for (int q = 0; q < 2; ++q)
#pragma unroll
        for (int n = 0; n < 2; ++n)
#pragma unroll
            for (int r = 0; r < 16; ++r) acc[q][n][r] = 0;

    // staging source (inverse-rotated chunk per thread)
    const int srow = tid >> 2;                               // 0..127
    const int soff = ((((tid & 3) - (tid >> 2) - (tid >> 4)) & 3) << 4);
    const int8_t* aS = A + (size_t)(bm + srow) * K + soff;
    const int8_t* bS = B + (size_t)(bn + srow) * K + soff;
    const size_t rstepA = (size_t)128 * K;   // 128 rows per A load round

    const int NT = K / BKB;

#define STAGE_A(SRC, DST)                                                    \
    {                                                                        \
        _Pragma("unroll")                                                    \
        for (int l = 0; l < 2; ++l)                                          \
            __builtin_amdgcn_global_load_lds(                                \
                (const __attribute__((address_space(1))) void*)((SRC) + l * rstepA), \
                (__attribute__((address_space(3))) void*)((DST) + l * 8192 + tid * 16), \
                16, 0, 0);                                                   \
    }
#define STAGE_B(SRC, DST)                                                    \
    __builtin_amdgcn_global_load_lds(                                        \
        (const __attribute__((address_space(1))) void*)(SRC),                \
        (__attribute__((address_space(3))) void*)((DST) + tid * 16), 16, 0, 0);

    // prologue: stage tile 0 into buffer 0
    STAGE_A(aS, &sA[0][0]);
    STAGE_B(bS, &sB[0][0]);
    asm volatile("s_waitcnt vmcnt(0)" ::: "memory");
    __builtin_amdgcn_s_barrier();
    asm volatile("" ::: "memory");

    for (int t = 0; t < NT; ++t) {
        const int cur = t & 1;
        const int8_t* cA = &sA[cur][0];
        const int8_t* cB = &sB[cur][0];
        int8_t* nA = &sA[cur ^ 1][0];
        int8_t* nB = &sB[cur ^ 1][0];
        const size_t knext = (size_t)(t + 1) * BKB;
        const bool pf = (t + 1 < NT);   // uniform

        // B-frags for the whole tile (4 x ds_read_b128)
        i32x4 bf[2][2];
#pragma unroll
        for (int n = 0; n < 2; ++n)
#pragma unroll
            for (int ks = 0; ks < 2; ++ks) {
                const int row = wn + n * 32 + l31;
                bf[n][ks] = *(const i32x4*)(cB + row * BKB +
                                            (((((ks << 1) | lhalf) + rot4) & 3) << 4));
            }

#pragma unroll
        for (int q = 0; q < 2; ++q) {
            // A-frags for M-subtile q (2 x ds_read_b128)
            i32x4 af[2];
            {
                const int arow = wm + q * 32 + l31;
#pragma unroll
                for (int ks = 0; ks < 2; ++ks)
                    af[ks] = *(const i32x4*)(cA + arow * BKB +
                                             (((((ks << 1) | lhalf) + rot4) & 3) << 4));
            }

            // prefetch next tile: A at q=0, B at q=1; flies under MFMA
            if (q == 0 && pf) STAGE_A(aS + knext, nA);
            if (q == 1 && pf) STAGE_B(bS + knext, nB);

            // 4 MFMA: M-subtile q x 2 N-tiles x 2 k-slices
#pragma unroll
            for (int n = 0; n < 2; ++n)
#pragma unroll
                for (int ks = 0; ks < 2; ++ks)
                    acc[q][n] = __builtin_amdgcn_mfma_i32_32x32x32_i8(
                        af[ks], bf[n][ks], acc[q][n], 0, 0, 0);
        }

        // tile boundary: drain this tile's prefetch, swap buffers
        asm volatile("s_waitcnt vmcnt(0)" ::: "memory");
        __builtin_amdgcn_s_barrier();
        asm volatile("" ::: "memory");
    }
#undef STAGE_A
#undef STAGE_B

    // Epilogue: out = fp32( bf16( bf16(acc*xs*ws) + bf16(bias) ) )
#pragma unroll
    for (int n = 0; n < 2; ++n) {
        const int col = bn + wn + n * 32 + l31;
        const float wsv = ws[col];
        const float bsv = __bfloat162float(__float2bfloat16(bias[col]));
#pragma unroll
        for (int q = 0; q < 2; ++q) {
            const int rowbase = bm + wm + q * 32 + 4 * lhalf;
#pragma unroll
            for (int r = 0; r < 16; ++r) {
                const int row = rowbase + (r & 3) + 8 * (r >> 2);
                const float v = (float)acc[q][n][r] * xs[row] * wsv;
                const float vb = __bfloat162float(__float2bfloat16(v));
                const float res = __bfloat162float(__float2bfloat16(vb + bsv));
                out[(size_t)row * N + col] = res;
            }
        }
    }
}

// ---------------------------------------------------------------------------
extern "C" void kernel_launch(void* const* d_in, const int* in_sizes, int n_in,
                              void* d_out, int out_size, void* d_ws, size_t ws_size,
                              hipStream_t stream)
{
    const float* x    = (const float*)d_in[0];   // [B,S,K] fp32
    const float* wfp  = (const float*)d_in[1];   // [N,K] fp32
    const float* bias = (const float*)d_in[2];   // [N] fp32
    float* out = (float*)d_out;                  // [M,N] fp32

    const int N = in_sizes[2];
    const int K = in_sizes[1] / N;
    const int M = in_sizes[0] / K;

    // workspace layout: w_i8[N*K] | x_i8[M*K] | w_scales[N] | x_scales[M]
    int8_t* w_i8 = (int8_t*)d_ws;
    int8_t* x_i8 = w_i8 + (size_t)N * K;
    float* w_scales = (float*)(x_i8 + (size_t)M * K);
    float* x_scales = w_scales + N;

    const int nrows = N + M;                     // one wave per row
    const int nblocks = (nrows + 3) / 4;         // 4 waves / 256-thread block
    quant_rows_wave<<<nblocks, 256, 0, stream>>>(wfp, x, w_i8, x_i8,
                                                 w_scales, x_scales,
                                                 N, nrows, K);

    dim3 grid(N / BN, M / BM);
    gemm_i8_256x128<<<grid, 512, 0, stream>>>(x_i8, w_i8, x_scales, w_scales,
                                              bias, out, M, N, K);
}

// Round 7
// 444.669 us; speedup vs baseline: 1.0287x; 1.0189x over previous
//
#include <hip/hip_runtime.h>
#include <hip/hip_bf16.h>
#include <stdint.h>

// Int8Linear: per-row symmetric int8 quant (w per-output-channel, x per-token),
// int8 GEMM (exact int32 accum via MFMA i8), fused dequant + bf16 bias epilogue.
// M=8192, K=4096, N=4096 for this problem instance.
//
// R10 changes vs R9:
//  - REVERT to R5's geometry (256x256 block, 8 waves 2Mx4N, wave tile 128x64):
//    R7-R9's 64x64 wave tile was LDS-traffic-bound (1.375 KB/MFMA vs 1.0) and
//    barrier-amortization-poor (8 vs 32 MFMA/wave/barrier); zero conflicts
//    (R9) didn't help because conflicts were overlapped there.
//  - KEEP R9's add-rotation swizzle (verified 0 bank conflicts at 64B rows):
//    sw(row) = (row + (row>>2)) & 3, phys = (log + sw) & 3.
//  - NEW: counted vmcnt, never 0 in main loop (T4): BK=64, FOUR LDS buffers
//    (128 KB), depth-3 prefetch. Tile t issues stages for t+3; tile end waits
//    vmcnt(8) -> only loads issued 2-3 tiles ago must have landed (~free).
//    One s_barrier per K-tile (R5's count; NOT R6's failed per-phase lockstep).

using i32x4  = __attribute__((ext_vector_type(4))) int;
using i32x16 = __attribute__((ext_vector_type(16))) int;

#define BM 256
#define BN 256
#define BKB 64    // K-bytes (= int8 k-elems) per LDS tile
#define NBUF 4    // depth-3 prefetch

// ---------------------------------------------------------------------------
// Fused per-row quantization for both W [N,K] and X [M,K]; one WAVE per row.
// ---------------------------------------------------------------------------
__global__ __launch_bounds__(256) void quant_rows_wave(
    const float* __restrict__ w_in, const float* __restrict__ x_in,
    int8_t* __restrict__ w_q, int8_t* __restrict__ x_q,
    float* __restrict__ w_s, float* __restrict__ x_s,
    int nw, int nrows, int K)
{
    const int wave_id = (int)((blockIdx.x * (unsigned)blockDim.x + threadIdx.x) >> 6);
    if (wave_id >= nrows) return;
    const int lane = threadIdx.x & 63;

    const bool is_w = (wave_id < nw);
    const int row = is_w ? wave_id : (wave_id - nw);
    const float* r = (is_w ? w_in : x_in) + (size_t)row * K;
    int8_t* qout   = (is_w ? w_q : x_q) + (size_t)row * K;
    float* scales  = is_w ? w_s : x_s;

    float4 v[16];
#pragma unroll
    for (int i = 0; i < 16; ++i)
        v[i] = *(const float4*)(r + i * 256 + lane * 4);

    float amax = 0.f;
#pragma unroll
    for (int i = 0; i < 16; ++i) {
        amax = fmaxf(amax, fmaxf(fmaxf(fabsf(v[i].x), fabsf(v[i].y)),
                                 fmaxf(fabsf(v[i].z), fabsf(v[i].w))));
    }

#pragma unroll
    for (int off = 32; off >= 1; off >>= 1)
        amax = fmaxf(amax, __shfl_xor(amax, off));

    const float scale = fmaxf(amax / 127.0f, 1e-12f);
    if (lane == 0) scales[row] = scale;
    const float inv = 1.0f / scale;

#pragma unroll
    for (int i = 0; i < 16; ++i) {
        float q0 = fminf(fmaxf(rintf(v[i].x * inv), -128.f), 127.f);
        float q1 = fminf(fmaxf(rintf(v[i].y * inv), -128.f), 127.f);
        float q2 = fminf(fmaxf(rintf(v[i].z * inv), -128.f), 127.f);
        float q3 = fminf(fmaxf(rintf(v[i].w * inv), -128.f), 127.f);
        union { signed char c[4]; int i32; } u;
        u.c[0] = (signed char)(int)q0;
        u.c[1] = (signed char)(int)q1;
        u.c[2] = (signed char)(int)q2;
        u.c[3] = (signed char)(int)q3;
        *(int*)(qout + i * 256 + lane * 4) = u.i32;
    }
}

// ---------------------------------------------------------------------------
// int8 GEMM: C[M][N] = A[M][K] . B[N][K]^T, int32 accum, fused dequant.
// 256x256 tile, BK=64 (64B rows), 8 waves (2M x 4N, 128x64 each),
// 32x32x32 i8 MFMA, 4-buffer LDS (128 KB), depth-3 prefetch, counted vmcnt.
//
// LDS: row-major [256 rows][64 B], 16B chunks, add-rotation swizzle
// (R9-verified conflict-free at 64B rows):
//   sw(row) = (row + (row>>2)) & 3;  phys_chunk = (log_chunk + sw) & 3
// Staged via global_load_lds (linear dest: round l, thread t -> byte
// l*8192 + t*16, i.e. row = l*128 + (t>>2), phys = t&3) with the INVERSE
// rotation on the per-thread global source chunk:
//   log = ((t&3) - (t>>2) - (t>>4)) & 3    (l*128, bm contribute 0 mod 4
//   to both row and row>>2 terms -> l-independent).
//
// Frag reads (32x32x32 i8): lane reads 16B at row = base + l31 (base mult.
// of 32), log = ks*2 + lhalf (ks=0..1), phys = (log + rot4) & 3 with
// rot4 = (l31 + (l31>>2)) & 3.
// C/D: col = lane&31, row = (reg&3) + 8*(reg>>2) + 4*(lane>>5)  [m74/m101]
//
// Pipeline: prologue stages tiles 0,1,2 (12 loads/thread), vmcnt(8), barrier.
// Tile t: read 12 b128 frags from buf[t&3]; issue 4 stage loads for t+3
// into buf[(t+3)&3]; 16 MFMA; counted wait (steady: vmcnt(8) -> t+1's 4
// loads, issued 2-3 tiles ago, landed; tail: vmcnt(4)/vmcnt(0)); s_barrier.
// WAR audit: buf[(t+3)&3] last read in tile t-1; those ds_reads completed
// before t-1's closing barrier (lgkm deps precede MFMA, MFMA precedes
// barrier arrival); stages for t+3 issued after that barrier. Safe.
// ---------------------------------------------------------------------------
__global__ __launch_bounds__(512, 2) void gemm_i8_p3(
    const int8_t* __restrict__ A,   // [M][K] x_i8
    const int8_t* __restrict__ B,   // [N][K] w_i8
    const float*  __restrict__ xs,  // [M]
    const float*  __restrict__ ws,  // [N]
    const float*  __restrict__ bias,// [N]
    float*        __restrict__ out, // [M][N] fp32
    int M, int N, int K)
{
    __shared__ int8_t sA[NBUF][BM * BKB];   // 4 x 16 KiB
    __shared__ int8_t sB[NBUF][BN * BKB];   // 4 x 16 KiB

    const int tid   = threadIdx.x;
    const int wave  = tid >> 6;
    const int lane  = tid & 63;
    const int l31   = lane & 31;
    const int lhalf = lane >> 5;                // 0/1
    const int rot4  = (l31 + (l31 >> 2)) & 3;   // read-side rotation

    const int bm = blockIdx.y * BM;
    const int bn = blockIdx.x * BN;
    const int wm = (wave >> 2) * 128;   // 2 M-groups
    const int wn = (wave & 3) * 64;     // 4 N-groups

    i32x16 acc[4][2];                   // wave tile 128x64: 128 acc regs
#pragma unroll
    for (int q = 0; q < 4; ++q)
#pragma unroll
        for (int n = 0; n < 2; ++n)
#pragma unroll
            for (int r = 0; r < 16; ++r) acc[q][n][r] = 0;

    // per-thread ds_read byte offsets (hoisted out of the K-loop)
    int aoff[4][2], boff[2][2];
#pragma unroll
    for (int q = 0; q < 4; ++q)
#pragma unroll
        for (int ks = 0; ks < 2; ++ks)
            aoff[q][ks] = (wm + q * 32 + l31) * BKB +
                          (((((ks << 1) | lhalf) + rot4) & 3) << 4);
#pragma unroll
    for (int n = 0; n < 2; ++n)
#pragma unroll
        for (int ks = 0; ks < 2; ++ks)
            boff[n][ks] = (wn + n * 32 + l31) * BKB +
                          (((((ks << 1) | lhalf) + rot4) & 3) << 4);

    // staging source (inverse-rotated chunk per thread; R9-verified)
    const int srow = tid >> 2;                               // 0..127
    const int soff = ((((tid & 3) - (tid >> 2) - (tid >> 4)) & 3) << 4);
    const int8_t* aS = A + (size_t)(bm + srow) * K + soff;
    const int8_t* bS = B + (size_t)(bn + srow) * K + soff;
    const size_t rstep = (size_t)128 * K;   // 128 rows per load round

    const int NT = K / BKB;   // 64

#define STAGE(SRC, DSTBASE)                                                  \
    {                                                                        \
        _Pragma("unroll")                                                    \
        for (int l = 0; l < 2; ++l)                                          \
            __builtin_amdgcn_global_load_lds(                                \
                (const __attribute__((address_space(1))) void*)((SRC) + l * rstep), \
                (__attribute__((address_space(3))) void*)((DSTBASE) + l * 8192 + tid * 16), \
                16, 0, 0);                                                   \
    }

    // prologue: stage tiles 0,1,2 (vmcnt order: oldest 4 = tile 0)
#pragma unroll
    for (int p = 0; p < 3; ++p) {
        STAGE(aS + p * BKB, &sA[p][0]);
        STAGE(bS + p * BKB, &sB[p][0]);
    }
    asm volatile("s_waitcnt vmcnt(8)" ::: "memory");   // tile 0 landed
    __builtin_amdgcn_s_barrier();
    asm volatile("" ::: "memory");

    for (int t = 0; t < NT; ++t) {
        const int8_t* cA = &sA[t & 3][0];
        const int8_t* cB = &sB[t & 3][0];
        const bool pf = (t + 3 < NT);                       // uniform
        const size_t knext = (size_t)(t + 3) * BKB;
        int8_t* nA = &sA[(t + 3) & 3][0];
        int8_t* nB = &sB[(t + 3) & 3][0];

        // B-frags for the whole tile (4 x ds_read_b128)
        i32x4 bf[2][2];
#pragma unroll
        for (int n = 0; n < 2; ++n)
#pragma unroll
            for (int ks = 0; ks < 2; ++ks)
                bf[n][ks] = *(const i32x4*)(cB + boff[n][ks]);

#pragma unroll
        for (int q = 0; q < 4; ++q) {
            i32x4 af[2];
#pragma unroll
            for (int ks = 0; ks < 2; ++ks)
                af[ks] = *(const i32x4*)(cA + aoff[q][ks]);

            // stage tile t+3: A at q=0, B at q=1 (flies ~3 tiles)
            if (q == 0 && pf) STAGE(aS + knext, nA);
            if (q == 1 && pf) STAGE(bS + knext, nB);

            // 4 MFMA: subtile q x 2 N x 2 k-slices
#pragma unroll
            for (int n = 0; n < 2; ++n)
#pragma unroll
                for (int ks = 0; ks < 2; ++ks)
                    acc[q][n] = __builtin_amdgcn_mfma_i32_32x32x32_i8(
                        af[ks], bf[n][ks], acc[q][n], 0, 0, 0);
        }

        // counted wait: ensure tile t+1's 4 loads landed; keep rest in flight
        if (t + 3 < NT) {
            asm volatile("s_waitcnt vmcnt(8)" ::: "memory");
        } else if (t + 3 == NT) {
            asm volatile("s_waitcnt vmcnt(4)" ::: "memory");
        } else if (t + 2 == NT) {
            asm volatile("s_waitcnt vmcnt(0)" ::: "memory");
        }
        __builtin_amdgcn_s_barrier();
        asm volatile("" ::: "memory");
    }
#undef STAGE

    // Epilogue: out = fp32( bf16( bf16(acc*xs*ws) + bf16(bias) ) )
#pragma unroll
    for (int n = 0; n < 2; ++n) {
        const int col = bn + wn + n * 32 + l31;
        const float wsv = ws[col];
        const float bsv = __bfloat162float(__float2bfloat16(bias[col]));
#pragma unroll
        for (int q = 0; q < 4; ++q) {
            const int rowbase = bm + wm + q * 32 + 4 * lhalf;
#pragma unroll
            for (int r = 0; r < 16; ++r) {
                const int row = rowbase + (r & 3) + 8 * (r >> 2);
                const float v = (float)acc[q][n][r] * xs[row] * wsv;
                const float vb = __bfloat162float(__float2bfloat16(v));
                const float res = __bfloat162float(__float2bfloat16(vb + bsv));
                out[(size_t)row * N + col] = res;
            }
        }
    }
}

// ---------------------------------------------------------------------------
extern "C" void kernel_launch(void* const* d_in, const int* in_sizes, int n_in,
                              void* d_out, int out_size, void* d_ws, size_t ws_size,
                              hipStream_t stream)
{
    const float* x    = (const float*)d_in[0];   // [B,S,K] fp32
    const float* wfp  = (const float*)d_in[1];   // [N,K] fp32
    const float* bias = (const float*)d_in[2];   // [N] fp32
    float* out = (float*)d_out;                  // [M,N] fp32

    const int N = in_sizes[2];
    const int K = in_sizes[1] / N;
    const int M = in_sizes[0] / K;

    // workspace layout: w_i8[N*K] | x_i8[M*K] | w_scales[N] | x_scales[M]
    int8_t* w_i8 = (int8_t*)d_ws;
    int8_t* x_i8 = w_i8 + (size_t)N * K;
    float* w_scales = (float*)(x_i8 + (size_t)M * K);
    float* x_scales = w_scales + N;

    const int nrows = N + M;                     // one wave per row
    const int nblocks = (nrows + 3) / 4;         // 4 waves / 256-thread block
    quant_rows_wave<<<nblocks, 256, 0, stream>>>(wfp, x, w_i8, x_i8,
                                                 w_scales, x_scales,
                                                 N, nrows, K);

    dim3 grid(N / BN, M / BM);
    gemm_i8_p3<<<grid, 512, 0, stream>>>(x_i8, w_i8, x_scales, w_scales,
                                         bias, out, M, N, K);
}